// Round 1
// 66.143 us; speedup vs baseline: 1.0321x; 1.0321x over previous
//
#include <hip/hip_runtime.h>

// Problem: ctx[b,i,d] = tanh(emb[b,i,d] * mean_j emb[b,j,d])
// B=512, I=128, D=64, fp32 in / fp32 out. Memory-bound: 33.5 MB total traffic
// -> ~5.6 us at 6.3 TB/s achievable. Previous version (LDS-stash, 256 thr) ran
// ~23.7 us = 1.4 TB/s: occupancy/latency-limited (8 waves/CU) + 64 KB/block of
// LDS round-trip overhead. This version keeps the tile in REGISTERS, uses
// 512-thread blocks (16 waves/CU), and reduces partials via shfl_xor so LDS
// shrinks to 2.3 KB.

#define BB 512
#define II 128
#define DD 64
#define ELEMS_PER_BATCH (II * DD)               // 8192 floats
#define VEC_PER_BATCH   (ELEMS_PER_BATCH / 4)   // 2048 float4
#define BLOCK 512
#define VPT   (VEC_PER_BATCH / BLOCK)           // 4 float4 per thread (16 VGPRs)
#define WAVES (BLOCK / 64)                      // 8

typedef float f4 __attribute__((ext_vector_type(4)));

__device__ __forceinline__ float fast_tanh(float x) {
    // tanh(x) = 1 - 2/(e^{2x}+1). v_exp_f32 + v_rcp_f32.
    // x -> +inf: e=inf, rcp=0 -> 1.  x -> -inf: e=0, rcp(1)=1 -> -1.
    float e = __expf(2.0f * x);
    return __fmaf_rn(-2.0f, __builtin_amdgcn_rcpf(e + 1.0f), 1.0f);
}

__global__ __launch_bounds__(BLOCK, 4) void ctx_tanh_kernel(
        const float* __restrict__ emb, float* __restrict__ out) {
    // One block per batch. Row length = 64 floats = 16 float4, so vector
    // index j belongs to column-group j & 15; j = t + 512k keeps j%16 == t%16.
    __shared__ f4 s_part[WAVES * 16];   // per-(wave, colgroup) partial sums, 2 KB
    __shared__ f4 s_mean[16];           // 64 mean values

    const int b = blockIdx.x;
    const int t = threadIdx.x;
    const f4* __restrict__ gin  = (const f4*)(emb + (size_t)b * ELEMS_PER_BATCH);
    f4* __restrict__       gout = (f4*)(out + (size_t)b * ELEMS_PER_BATCH);

    // Phase 1: coalesced loads straight into registers; all 4 issued before use.
    f4 v[VPT];
    #pragma unroll
    for (int k = 0; k < VPT; ++k) v[k] = gin[t + BLOCK * k];

    // Per-thread column partial (all 4 vectors share colgroup t&15).
    f4 acc = v[0];
    #pragma unroll
    for (int k = 1; k < VPT; ++k) acc += v[k];

    // In-wave reduce: lanes t, t^16, t^32, t^48 share the same colgroup.
    acc.x += __shfl_xor(acc.x, 16); acc.y += __shfl_xor(acc.y, 16);
    acc.z += __shfl_xor(acc.z, 16); acc.w += __shfl_xor(acc.w, 16);
    acc.x += __shfl_xor(acc.x, 32); acc.y += __shfl_xor(acc.y, 32);
    acc.z += __shfl_xor(acc.z, 32); acc.w += __shfl_xor(acc.w, 32);

    const int lane = t & 63;
    const int wave = t >> 6;
    if (lane < 16) s_part[wave * 16 + lane] = acc;
    __syncthreads();

    // Phase 2: 16 threads fold the 8 wave-partials -> mean[4t..4t+3].
    if (t < 16) {
        f4 s = s_part[t];
        #pragma unroll
        for (int w = 1; w < WAVES; ++w) s += s_part[w * 16 + t];
        s *= (1.0f / (float)II);
        s_mean[t] = s;
    }
    __syncthreads();

    // Phase 3: scale + tanh from registers, nontemporal coalesced stores
    // (output is written once and never re-read -> don't pollute L2).
    const f4 m4 = s_mean[t & 15];
    #pragma unroll
    for (int k = 0; k < VPT; ++k) {
        f4 o;
        o.x = fast_tanh(v[k].x * m4.x);
        o.y = fast_tanh(v[k].y * m4.y);
        o.z = fast_tanh(v[k].z * m4.z);
        o.w = fast_tanh(v[k].w * m4.w);
        __builtin_nontemporal_store(o, &gout[t + BLOCK * k]);
    }
}

extern "C" void kernel_launch(void* const* d_in, const int* in_sizes, int n_in,
                              void* d_out, int out_size, void* d_ws, size_t ws_size,
                              hipStream_t stream) {
    const float* emb = (const float*)d_in[0];
    float* out = (float*)d_out;
    ctx_tanh_kernel<<<dim3(BB), dim3(BLOCK), 0, stream>>>(emb, out);
}